// Round 1
// 231.031 us; speedup vs baseline: 1.0442x; 1.0442x over previous
//
#include <hip/hip_runtime.h>

// IndRNN, 2 layers, diagonal recurrence: h[t] = relu(x[t] + w*h[t-1]) per layer.
// x: [T=2048, B=32, H=512] fp32. 16384 chains -> 256 blocks x 64 chains.
//
// R3 change vs R2: producer/consumer wave decoupling. The R2 single-wave design
// shared one vmcnt FIFO between loads and stores; the 6-bit vmcnt cap (63) forced
// every buffer-consume wait to drain to ~31 loads in flight/CU (~8KB) -> latency-
// bound at 2.3 TB/s. Now wave 0 is a pure DMA producer (global_load_lds width=16,
// 4-slot 64KiB LDS ring, 3 phases = 192 timesteps ahead, counted vmcnt(32) waits,
// never 0). Wave 1 runs the serial recurrence: ds_read_b32 (2 lanes/bank = free)
// + 4 VALU + fire-and-forget store; its vmcnt FIFO holds only stores and is never
// waited on. Raw s_barrier (no __syncthreads vmcnt(0) drain) + sched_barrier pins.

#define TSTEPS  2048
#define BATCH   32
#define HID     512
#define BH      (BATCH * HID)          /* 16384 chains */
#define PHASE_T 64                     /* timesteps per phase */
#define NPHASE  (TSTEPS / PHASE_T)     /* 32 */
#define NSLOT   4                      /* ring slots (power of 2) */
#define SLOT_FLOATS (PHASE_T * 64)     /* 4096 floats = 16 KiB */
#define SLOT_BYTES  (SLOT_FLOATS * 4)
#define LOADS_PER_PHASE (PHASE_T / 4)  /* 16 x 1KiB global_load_lds per phase */

typedef __attribute__((address_space(1))) const void* gas_cvp;
typedef __attribute__((address_space(3))) void*       las_vp;

__global__ __launch_bounds__(128, 1) void indrnn_pc_kernel(
    const float* __restrict__ x,
    const float* __restrict__ w_hh,
    const float* __restrict__ h0,
    float* __restrict__ out) {
  __shared__ float lds[NSLOT * SLOT_FLOATS];   // 64 KiB ring

  const int tid   = threadIdx.x;
  const int wave  = tid >> 6;
  const int lane  = tid & 63;
  const int cbase = blockIdx.x * 64;           // first chain of this block

  if (wave == 0) {
    // ---------------- producer (pure DMA wave) ----------------
    // One instruction moves 64 lanes x 16B = 1 KiB = 4 timesteps x 64 chains.
    // Lane l = j*16+i loads x[t0+j, chain cbase+4i .. +3] -> LDS linear dest
    // (lds_base + l*16), giving LDS layout [t][chain] with t-stride 256B.
    const int j = lane >> 4;                   // timestep within quad
    const int i = lane & 15;                   // chain quad
    const float* gp = x + cbase + (size_t)j * BH + i * 4;

    // Prologue: issue phases 0..2 (48 loads in flight), release phase 0.
#pragma unroll
    for (int p = 0; p < 3; ++p) {
      char* lbase = (char*)lds + p * SLOT_BYTES;
      const float* gq = gp + (size_t)p * PHASE_T * BH;
#pragma unroll
      for (int q = 0; q < LOADS_PER_PHASE; ++q) {
        __builtin_amdgcn_global_load_lds((gas_cvp)(gq + (size_t)q * 4 * BH),
                                         (las_vp)(lbase + q * 1024), 16, 0, 0);
      }
    }
    __builtin_amdgcn_sched_barrier(0);
    asm volatile("s_waitcnt vmcnt(32)" ::: "memory");   // phase 0 complete
    __builtin_amdgcn_s_barrier();                       // B0: release phase 0

    for (int p = 0; p < NPHASE; ++p) {
      const int ip = p + 3;                    // phase to prefetch
      if (ip < NPHASE) {
        // slot (ip&3) == ((p-1)&3): consumer finished phase p-1 before B_p.
        char* lbase = (char*)lds + (ip & (NSLOT - 1)) * SLOT_BYTES;
        const float* gq = gp + (size_t)ip * PHASE_T * BH;
#pragma unroll
        for (int q = 0; q < LOADS_PER_PHASE; ++q) {
          __builtin_amdgcn_global_load_lds((gas_cvp)(gq + (size_t)q * 4 * BH),
                                           (las_vp)(lbase + q * 1024), 16, 0, 0);
        }
      }
      __builtin_amdgcn_sched_barrier(0);
      // Guarantee phase p+1 resident before releasing it; counted, never 0
      // until drain. Outstanding newer than p+1: phases p+2, p+3 (16 each).
      if (p < NPHASE - 3)       asm volatile("s_waitcnt vmcnt(32)" ::: "memory");
      else if (p == NPHASE - 3) asm volatile("s_waitcnt vmcnt(16)" ::: "memory");
      else                      asm volatile("s_waitcnt vmcnt(0)"  ::: "memory");
      __builtin_amdgcn_s_barrier();            // B_{p+1}: release phase p+1
    }
  } else {
    // ---------------- consumer (serial recurrence wave) ----------------
    const int c   = cbase + lane;
    const int hid = c & (HID - 1);
    const float w1 = w_hh[hid];
    const float w2 = w_hh[HID + hid];
    float h1 = h0[c];
    float h2 = h0[BH + c];
    float* op = out + c;

    for (int p = 0; p < NPHASE; ++p) {
      __builtin_amdgcn_s_barrier();            // B_p: phase p resident
      __builtin_amdgcn_sched_barrier(0);       // keep ds_reads after barrier
      const float* lb = lds + (p & (NSLOT - 1)) * SLOT_FLOATS + lane;
      float* ob = op + (size_t)p * PHASE_T * BH;
#pragma unroll
      for (int u = 0; u < PHASE_T; ++u) {
        const float xv = lb[u * 64];           // ds_read_b32, 2 lanes/bank: free
        h1 = fmaxf(fmaf(w1, h1, xv), 0.0f);
        h2 = fmaxf(fmaf(w2, h2, h1), 0.0f);
        ob[(size_t)u * BH] = h2;               // fire-and-forget, never waited
      }
      __builtin_amdgcn_sched_barrier(0);       // keep reads before next barrier
    }
    __builtin_amdgcn_s_barrier();              // match producer's final barrier
  }
}

extern "C" void kernel_launch(void* const* d_in, const int* in_sizes, int n_in,
                              void* d_out, int out_size, void* d_ws, size_t ws_size,
                              hipStream_t stream) {
  const float* x    = (const float*)d_in[0];
  const float* w_hh = (const float*)d_in[1];
  const float* h0   = (const float*)d_in[2];
  float* out        = (float*)d_out;

  dim3 grid(BH / 64);   // 256 blocks = 1 per CU
  dim3 block(128);      // wave 0: producer DMA; wave 1: consumer recurrence
  hipLaunchKernelGGL(indrnn_pc_kernel, grid, block, 0, stream,
                     x, w_hh, h0, out);
}